// Round 4
// baseline (594.317 us; speedup 1.0000x reference)
//
#include <hip/hip_runtime.h>

#define B_  2
#define S_  1024
#define D_  4096
#define H_  32
#define HD_ 128
#define T_  (B_*S_)   // 2048 tokens

typedef int   i32x4 __attribute__((ext_vector_type(4)));
typedef float f32x4 __attribute__((ext_vector_type(4)));
typedef unsigned short u16;

__device__ __forceinline__ u16 f2bf(float f) {
  unsigned int u = __float_as_uint(f);
  u += 0x7fffu + ((u >> 16) & 1u);     // round-to-nearest-even
  return (u16)(u >> 16);
}
__device__ __forceinline__ float bf2f(u16 h) {
  return __uint_as_float(((unsigned int)h) << 16);
}
__device__ __forceinline__ void gload_lds16(const void* g, void* l) {
  __builtin_amdgcn_global_load_lds(
      (const __attribute__((address_space(1))) unsigned int*)g,
      (__attribute__((address_space(3))) unsigned int*)l, 16, 0, 0);
}
__device__ __forceinline__ void mfma16(i32x4 a, i32x4 b, f32x4& c) {
  asm("v_mfma_f32_16x16x32_bf16 %0, %1, %2, %0" : "+v"(c) : "v"(a), "v"(b));
}
__device__ __forceinline__ void mfma16a(i32x4 a, i32x4 b, f32x4& c) {
  asm("v_mfma_f32_16x16x32_bf16 %0, %1, %2, %0" : "+a"(c) : "v"(a), "v"(b));
}

// ---------------- f32 -> bf16 convert (vectorized, 8 elem/thread) ----------
__global__ __launch_bounds__(256) void cvt_bf16(const float* __restrict__ in,
                                                u16* __restrict__ out, int n8) {
  int i = blockIdx.x * 256 + threadIdx.x;
  if (i >= n8) return;
  const float4* p = (const float4*)in + (size_t)i * 2;
  float4 a = p[0], b = p[1];
  u16 us[8] = {f2bf(a.x), f2bf(a.y), f2bf(a.z), f2bf(a.w),
               f2bf(b.x), f2bf(b.y), f2bf(b.z), f2bf(b.w)};
  *(uint4*)(out + (size_t)i * 8) = *(uint4*)us;
}

// ---- stage one 128x64 bf16 tile: linear LDS dest, pre-swizzled source
// lane k of wave w, load l -> LDS byte (w*2+l)*1024 + k*16  (rows of 128B)
// stored slot16 s at row r holds logical col16 s^(r&7)
__device__ __forceinline__ void stage_half(const u16* __restrict__ g, int ldk,
                                           int row0, int k0, u16* lds,
                                           int wid, int lane) {
  const int rsub = lane >> 3;
  const int c16  = (lane & 7) ^ rsub;
#pragma unroll
  for (int l = 0; l < 2; ++l) {
    const int r = (wid * 2 + l) * 8 + rsub;
    gload_lds16(g + (size_t)(row0 + r) * ldk + k0 + c16 * 8,
                lds + (wid * 2 + l) * 512);
  }
}

// -------- 128x256 2-phase GEMM (T1+T2+T3+T4+T5, kk-outer MFMA), C = A*W^T --
// Parts per K-tile: {B0, B1, A} (each 128x64 = one stage_half = 2 loads/wave).
// QKV=1: scatter bf16 into 3 buffers of N=4096. QKV=0: f32 into Of (N=NB*256).
template <int QKV>
__global__ __launch_bounds__(512, 2) void gemm2p(const u16* __restrict__ A,
                                                 const u16* __restrict__ W,
                                                 u16* __restrict__ O0,
                                                 u16* __restrict__ O1,
                                                 u16* __restrict__ O2,
                                                 float* __restrict__ Of,
                                                 int MB, int NB, int K) {
  __shared__ __align__(16) u16 LA[2][128 * 64];     // slot, row*64+col (32KB)
  __shared__ __align__(16) u16 LB[2][2][128 * 64];  // slot, half      (64KB)
  const int nwg = MB * NB;                 // grids are %8==0 (768 / 256)
  const int cpx = nwg >> 3;
  const int bid = blockIdx.x;
  const int swz = (bid & 7) * cpx + (bid >> 3);   // T1: XCD chunk
  const int bm = swz % MB, bn = swz / MB;
  const int m0 = bm * 128, n0 = bn * 256;
  const int tid = threadIdx.x, wid = tid >> 6, lane = tid & 63;
  const int wr = wid >> 2, wc = wid & 3;          // 2x4 wave grid, 64x64/wave
  const int fr = lane & 15, fq = lane >> 4;
  const int nkt = K >> 6;
  f32x4 acc[4][4] = {};

  auto STAGE = [&](int gidx) {   // gidx = tile*3 + part, parts {B0,B1,A}
    if (gidx >= 3 * nkt) return;
    const int t = gidx / 3, part = gidx - 3 * t, slot = t & 1, k0 = t * 64;
    if (part < 2)
      stage_half(W, K, n0 + part * 128, k0, &LB[slot][part][0], wid, lane);
    else
      stage_half(A, K, m0, k0, &LA[slot][0], wid, lane);
  };

  // prologue: t0 {B0,B1,A} + t1 {B0,B1}; wait t0 landed (6 of 10 loads)
  for (int g = 0; g < 5; ++g) STAGE(g);
  asm volatile("s_waitcnt vmcnt(4)" ::: "memory");
  __builtin_amdgcn_s_barrier();

  for (int t = 0; t < nkt; ++t) {
    const int slot = t & 1;
    i32x4 af[2][2], bfr[4][2];
    // ---------------- phase 0: mi {0,1}; read all B frags (live both phases)
#pragma unroll
    for (int i = 0; i < 2; ++i)
#pragma unroll
      for (int kk = 0; kk < 2; ++kk) {
        const int r = wr * 64 + i * 16 + fr;
        const int s16 = (kk * 4 + fq) ^ (r & 7);
        af[i][kk] = *(const i32x4*)&LA[slot][r * 64 + s16 * 8];
      }
#pragma unroll
    for (int ni = 0; ni < 4; ++ni)
#pragma unroll
      for (int kk = 0; kk < 2; ++kk) {
        const int rr = (wc & 1) * 64 + ni * 16 + fr;
        const int s16 = (kk * 4 + fq) ^ (rr & 7);
        bfr[ni][kk] = *(const i32x4*)&LB[slot][wc >> 1][rr * 64 + s16 * 8];
      }
    STAGE(3 * t + 5);                       // tile t+1: A  (slot flips: WAR-safe)
    __builtin_amdgcn_s_barrier();
    asm volatile("s_waitcnt lgkmcnt(0)" ::: "memory");
    __builtin_amdgcn_sched_barrier(0);
    __builtin_amdgcn_s_setprio(1);
#pragma unroll
    for (int kk = 0; kk < 2; ++kk)          // kk OUTER: dep distance 8
#pragma unroll
      for (int i = 0; i < 2; ++i)
#pragma unroll
        for (int ni = 0; ni < 4; ++ni)
          mfma16a(af[i][kk], bfr[ni][kk], acc[i][ni]);
    __builtin_amdgcn_s_setprio(0);
    __builtin_amdgcn_s_barrier();
    // ---------------- phase 1: mi {2,3}
#pragma unroll
    for (int i = 0; i < 2; ++i)
#pragma unroll
      for (int kk = 0; kk < 2; ++kk) {
        const int r = wr * 64 + (2 + i) * 16 + fr;
        const int s16 = (kk * 4 + fq) ^ (r & 7);
        af[i][kk] = *(const i32x4*)&LA[slot][r * 64 + s16 * 8];
      }
    STAGE(3 * t + 6);                       // tile t+2: B0 (post-ph0-barrier: WAR-safe)
    STAGE(3 * t + 7);                       // tile t+2: B1
    if (t < nkt - 2) asm volatile("s_waitcnt vmcnt(4)" ::: "memory");
    else             asm volatile("s_waitcnt vmcnt(0)" ::: "memory");
    __builtin_amdgcn_s_barrier();
    asm volatile("s_waitcnt lgkmcnt(0)" ::: "memory");
    __builtin_amdgcn_sched_barrier(0);
    __builtin_amdgcn_s_setprio(1);
#pragma unroll
    for (int kk = 0; kk < 2; ++kk)
#pragma unroll
      for (int i = 0; i < 2; ++i)
#pragma unroll
        for (int ni = 0; ni < 4; ++ni)
          mfma16a(af[i][kk], bfr[ni][kk], acc[2 + i][ni]);
    __builtin_amdgcn_s_setprio(0);
    __builtin_amdgcn_s_barrier();
  }

  // epilogue: D(i,j): col = lane&15, row = (lane>>4)*4 + reg
  if (QKV) {
    u16* Ob = (n0 < 4096) ? O0 : (n0 < 8192 ? O1 : O2);
    const int nc = n0 & 4095;
#pragma unroll
    for (int mi = 0; mi < 4; ++mi)
#pragma unroll
      for (int ni = 0; ni < 4; ++ni) {
        const int col = nc + wc * 64 + ni * 16 + fr;
#pragma unroll
        for (int r = 0; r < 4; ++r) {
          const int row = m0 + wr * 64 + mi * 16 + fq * 4 + r;
          Ob[(size_t)row * 4096 + col] = f2bf(acc[mi][ni][r]);
        }
      }
  } else {
    const int Nn = NB * 256;
#pragma unroll
    for (int mi = 0; mi < 4; ++mi)
#pragma unroll
      for (int ni = 0; ni < 4; ++ni) {
        const int col = n0 + wc * 64 + ni * 16 + fr;
#pragma unroll
        for (int r = 0; r < 4; ++r) {
          const int row = m0 + wr * 64 + mi * 16 + fq * 4 + r;
          Of[(size_t)row * Nn + col] = acc[mi][ni][r];
        }
      }
  }
}

// ---------------- RoPE in-place on bf16 q/k (host-provided cos/sin) --------
__global__ __launch_bounds__(256) void rope_k(u16* __restrict__ q,
                                              u16* __restrict__ k,
                                              const float* __restrict__ cosb,
                                              const float* __restrict__ sinb) {
  u16* t = blockIdx.y ? k : q;
  size_t idx = ((size_t)blockIdx.x * 256 + threadIdx.x) * 8;
  int s  = (int)((idx / D_) % S_);
  int d  = (int)(idx & (HD_ - 1));
  int i0 = d >> 1;
  u16 u[8];
  *(uint4*)u = *(const uint4*)&t[idx];
  float4 c  = *(const float4*)&cosb[s * (HD_ / 2) + i0];
  float4 sn = *(const float4*)&sinb[s * (HD_ / 2) + i0];
  float cs[4] = {c.x, c.y, c.z, c.w}, ss[4] = {sn.x, sn.y, sn.z, sn.w};
#pragma unroll
  for (int p = 0; p < 4; ++p) {
    float t0 = bf2f(u[2 * p]), t1 = bf2f(u[2 * p + 1]);
    u[2 * p]     = f2bf(t0 * cs[p] - t1 * ss[p]);
    u[2 * p + 1] = f2bf(t0 * ss[p] + t1 * cs[p]);
  }
  *(uint4*)&t[idx] = *(uint4*)u;
}

// ---------------- V transpose: (b,s,h,d) -> (b,h,d,s) ----------------------
__global__ __launch_bounds__(256) void transpose_v(const u16* __restrict__ v,
                                                   u16* __restrict__ vt) {
  __shared__ u16 tile[32][33];
  int s0 = blockIdx.x * 32, d0 = blockIdx.y * 32;
  int b = blockIdx.z / H_, h = blockIdx.z % H_;
  int tx = threadIdx.x & 31, ty = threadIdx.x >> 5;
#pragma unroll
  for (int r = 0; r < 32; r += 8)
    tile[ty + r][tx] = v[(size_t)(b * S_ + s0 + ty + r) * D_ + h * HD_ + d0 + tx];
  __syncthreads();
#pragma unroll
  for (int r = 0; r < 32; r += 8)
    vt[(size_t)((b * H_ + h) * HD_ + d0 + ty + r) * S_ + s0 + tx] = tile[tx][ty + r];
}

// ---------------- Flash attention: Q-tile 128, 8 waves x 16 q-rows ---------
__global__ __launch_bounds__(512) void flash_attn(const u16* __restrict__ qb,
                                                  const u16* __restrict__ kb,
                                                  const u16* __restrict__ vtb,
                                                  u16* __restrict__ ab) {
  __shared__ __align__(16) u16 Ks[64][136];
  __shared__ __align__(16) u16 Vs[128][72];
  __shared__ __align__(16) u16 Ps[8][16][72];
  const int qt = blockIdx.x, h = blockIdx.y, b = blockIdx.z;
  const int tid = threadIdx.x, wid = tid >> 6, lane = tid & 63;
  const int fr = lane & 15, fq = lane >> 4;
  const int q0 = qt * 128 + wid * 16;
  i32x4 qf[4];
  {
    size_t base = (size_t)(b * S_ + q0 + fr) * D_ + h * HD_;
#pragma unroll
    for (int kk = 0; kk < 4; ++kk) qf[kk] = *(const i32x4*)&qb[base + kk * 32 + fq * 8];
  }
  f32x4 oacc[8] = {};
  float m_i[4] = {-1e30f, -1e30f, -1e30f, -1e30f};
  float l_i[4] = {0.f, 0.f, 0.f, 0.f};
  const float sc = 0.08838834764831845f;  // 1/sqrt(128)

  for (int k0 = 0; k0 < S_; k0 += 64) {
    __syncthreads();
    for (int c = tid; c < 1024; c += 512) {
      int row = c >> 4, col = (c & 15) * 8;
      *(uint4*)&Ks[row][col] =
          *(const uint4*)&kb[(size_t)(b * S_ + k0 + row) * D_ + h * HD_ + col];
    }
    for (int c = tid; c < 1024; c += 512) {
      int row = c >> 3, col = (c & 7) * 8;
      *(uint4*)&Vs[row][col] =
          *(const uint4*)&vtb[(size_t)((b * H_ + h) * HD_ + row) * S_ + k0 + col];
    }
    __syncthreads();
    f32x4 sacc[4] = {};
#pragma unroll
    for (int kk = 0; kk < 4; ++kk)      // kk OUTER: dep distance 4
#pragma unroll
      for (int nb = 0; nb < 4; ++nb)
        mfma16(qf[kk], *(const i32x4*)&Ks[nb * 16 + fr][kk * 32 + fq * 8], sacc[nb]);
#pragma unroll
    for (int r = 0; r < 4; ++r) {
      float s0 = sacc[0][r] * sc, s1 = sacc[1][r] * sc;
      float s2 = sacc[2][r] * sc, s3 = sacc[3][r] * sc;
      float mx = fmaxf(fmaxf(s0, s1), fmaxf(s2, s3));
#pragma unroll
      for (int o = 1; o < 16; o <<= 1) mx = fmaxf(mx, __shfl_xor(mx, o));
      float newm = fmaxf(m_i[r], mx);
      float fsc = __expf(m_i[r] - newm);
      m_i[r] = newm;
      float p0 = __expf(s0 - newm), p1 = __expf(s1 - newm);
      float p2 = __expf(s2 - newm), p3 = __expf(s3 - newm);
      float sum = p0 + p1 + p2 + p3;
#pragma unroll
      for (int o = 1; o < 16; o <<= 1) sum += __shfl_xor(sum, o);
      l_i[r] = l_i[r] * fsc + sum;
#pragma unroll
      for (int db = 0; db < 8; ++db) oacc[db][r] *= fsc;
      Ps[wid][fq * 4 + r][0 * 16 + fr] = f2bf(p0);
      Ps[wid][fq * 4 + r][1 * 16 + fr] = f2bf(p1);
      Ps[wid][fq * 4 + r][2 * 16 + fr] = f2bf(p2);
      Ps[wid][fq * 4 + r][3 * 16 + fr] = f2bf(p3);
    }
    i32x4 pf0 = *(const i32x4*)&Ps[wid][fr][fq * 8];
    i32x4 pf1 = *(const i32x4*)&Ps[wid][fr][32 + fq * 8];
#pragma unroll
    for (int db = 0; db < 8; ++db)      // split rounds: dep distance 8
      mfma16(pf0, *(const i32x4*)&Vs[db * 16 + fr][fq * 8], oacc[db]);
#pragma unroll
    for (int db = 0; db < 8; ++db)
      mfma16(pf1, *(const i32x4*)&Vs[db * 16 + fr][32 + fq * 8], oacc[db]);
  }
#pragma unroll
  for (int r = 0; r < 4; ++r) {
    float inv = 1.0f / l_i[r];
    size_t rowbase = (size_t)(b * S_ + q0 + fq * 4 + r) * D_ + h * HD_;
#pragma unroll
    for (int db = 0; db < 8; ++db)
      ab[rowbase + db * 16 + fr] = f2bf(oacc[db][r] * inv);
  }
}

// ---------------------------------------------------------------------------
extern "C" void kernel_launch(void* const* d_in, const int* in_sizes, int n_in,
                              void* d_out, int out_size, void* d_ws, size_t ws_size,
                              hipStream_t stream) {
  const float* x    = (const float*)d_in[0];
  const float* wq   = (const float*)d_in[1];
  const float* wk   = (const float*)d_in[2];
  const float* wv   = (const float*)d_in[3];
  const float* wo   = (const float*)d_in[4];
  const float* fcos = (const float*)d_in[7];
  const float* fsin = (const float*)d_in[8];
  float* out = (float*)d_out;

  u16* xb  = (u16*)d_ws;                      // T*D
  u16* wqb = xb + (size_t)T_ * D_;            // D*D each; wq|wk|wv CONTIGUOUS
  u16* wkb = wqb + (size_t)D_ * D_;
  u16* wvb = wkb + (size_t)D_ * D_;
  u16* wob = wvb + (size_t)D_ * D_;
  u16* qb  = wob + (size_t)D_ * D_;           // T*D each
  u16* kb  = qb + (size_t)T_ * D_;
  u16* vb  = kb + (size_t)T_ * D_;
  u16* vtb = vb + (size_t)T_ * D_;
  u16* ab  = vtb + (size_t)T_ * D_;

  cvt_bf16<<<T_ * D_ / 8 / 256, 256, 0, stream>>>(x, xb, T_ * D_ / 8);
  cvt_bf16<<<D_ * D_ / 8 / 256, 256, 0, stream>>>(wq, wqb, D_ * D_ / 8);
  cvt_bf16<<<D_ * D_ / 8 / 256, 256, 0, stream>>>(wk, wkb, D_ * D_ / 8);
  cvt_bf16<<<D_ * D_ / 8 / 256, 256, 0, stream>>>(wv, wvb, D_ * D_ / 8);
  cvt_bf16<<<D_ * D_ / 8 / 256, 256, 0, stream>>>(wo, wob, D_ * D_ / 8);

  // fused QKV: M=2048, N=12288, K=4096 -> 16x48 = 768 blocks (3.0/CU exact)
  gemm2p<1><<<768, 512, 0, stream>>>(xb, wqb, qb, kb, vb, nullptr, 16, 48, D_);

  rope_k<<<dim3(T_ * D_ / 8 / 256, 2), 256, 0, stream>>>(qb, kb, fcos, fsin);
  transpose_v<<<dim3(S_ / 32, HD_ / 32, B_ * H_), 256, 0, stream>>>(vb, vtb);
  flash_attn<<<dim3(S_ / 128, H_, B_), 512, 0, stream>>>(qb, kb, vtb, ab);

  // output projection: M=2048, N=4096 -> 16x16 = 256 blocks (1.0/CU exact)
  gemm2p<0><<<256, 512, 0, stream>>>(ab, wob, nullptr, nullptr, nullptr, out, 16, 16, D_);
}

// Round 5
// 556.157 us; speedup vs baseline: 1.0686x; 1.0686x over previous
//
#include <hip/hip_runtime.h>

#define B_  2
#define S_  1024
#define D_  4096
#define H_  32
#define HD_ 128
#define T_  (B_*S_)   // 2048 tokens

typedef short s16x8 __attribute__((ext_vector_type(8)));   // 8 bf16 (4 VGPRs)
typedef float f32x4 __attribute__((ext_vector_type(4)));
typedef unsigned short u16;

__device__ __forceinline__ u16 f2bf(float f) {
  unsigned int u = __float_as_uint(f);
  u += 0x7fffu + ((u >> 16) & 1u);     // round-to-nearest-even
  return (u16)(u >> 16);
}
__device__ __forceinline__ float bf2f(u16 h) {
  return __uint_as_float(((unsigned int)h) << 16);
}
__device__ __forceinline__ void gload_lds16(const void* g, void* l) {
  __builtin_amdgcn_global_load_lds(
      (const __attribute__((address_space(1))) unsigned int*)g,
      (__attribute__((address_space(3))) unsigned int*)l, 16, 0, 0);
}
#define MFMA16(a, b, c) __builtin_amdgcn_mfma_f32_16x16x32_bf16((a), (b), (c), 0, 0, 0)

// ---------------- f32 -> bf16 convert (vectorized, 8 elem/thread) ----------
__global__ __launch_bounds__(256) void cvt_bf16(const float* __restrict__ in,
                                                u16* __restrict__ out, int n8) {
  int i = blockIdx.x * 256 + threadIdx.x;
  if (i >= n8) return;
  const float4* p = (const float4*)in + (size_t)i * 2;
  float4 a = p[0], b = p[1];
  u16 us[8] = {f2bf(a.x), f2bf(a.y), f2bf(a.z), f2bf(a.w),
               f2bf(b.x), f2bf(b.y), f2bf(b.z), f2bf(b.w)};
  *(uint4*)(out + (size_t)i * 8) = *(uint4*)us;
}

// ---- stage one 128x64 bf16 tile with 4 waves (4 chunks of 8 rows each).
// Linear LDS dest (row-major [128][64]), pre-swizzled global source:
// stored 16B-slot s at row r holds logical col16 s^(r&7)  [T2, proven R2-R4]
__device__ __forceinline__ void stage_tile4(const u16* __restrict__ g, int ldk,
                                            int row0, int k0, u16* lds,
                                            int wid, int lane) {
  const int rsub = lane >> 3;           // 0..7 row within chunk
  const int c16  = (lane & 7) ^ rsub;   // pre-swizzled source col16
#pragma unroll
  for (int l = 0; l < 4; ++l) {
    const int c = wid * 4 + l;          // chunk 0..15
    gload_lds16(g + (size_t)(row0 + c * 8 + rsub) * ldk + k0 + c16 * 8,
                lds + c * 512);
  }
}

// ---------- m97-style 128x128 GEMM, C = A[M,K] * W[N,K]^T, bf16 ------------
// 4 waves (2x2), per-wave 64x64, BK=64, single-buffered LDS, plain
// __syncthreads, builtin MFMA (compiler-scheduled interior), swizzled LDS.
// QKV=1: scatter bf16 into 3 buffers of N=4096. QKV=0: f32 into Of (N=NB*128).
template <int QKV>
__global__ __launch_bounds__(256) void gemm_m97(const u16* __restrict__ A,
                                                const u16* __restrict__ W,
                                                u16* __restrict__ O0,
                                                u16* __restrict__ O1,
                                                u16* __restrict__ O2,
                                                float* __restrict__ Of,
                                                int MB, int NB, int K) {
  __shared__ __align__(16) u16 LA[128 * 64];
  __shared__ __align__(16) u16 LB[128 * 64];
  const int nwg = MB * NB;                        // %8 == 0 for both grids
  const int cpx = nwg >> 3;
  const int bid = blockIdx.x;
  const int swz = (bid & 7) * cpx + (bid >> 3);   // T1: XCD chunking
  const int bm = swz % MB, bn = swz / MB;         // M-fastest: W-panel L2 reuse
  const int m0 = bm * 128, n0 = bn * 128;
  const int tid = threadIdx.x, wid = tid >> 6, lane = tid & 63;
  const int wr = wid >> 1, wc = wid & 1;          // 2x2 waves, 64x64 each
  const int fr = lane & 15, fq = lane >> 4;
  f32x4 acc[4][4] = {};

  for (int k0 = 0; k0 < K; k0 += 64) {
    stage_tile4(A, K, m0, k0, LA, wid, lane);
    stage_tile4(W, K, n0, k0, LB, wid, lane);
    __syncthreads();                 // drains vmcnt: tiles resident
    s16x8 af[4][2], bf[4][2];
#pragma unroll
    for (int mi = 0; mi < 4; ++mi)
#pragma unroll
      for (int kk = 0; kk < 2; ++kk) {
        const int r = wr * 64 + mi * 16 + fr;
        const int s16 = (kk * 4 + fq) ^ (r & 7);
        af[mi][kk] = *(const s16x8*)&LA[r * 64 + s16 * 8];
      }
#pragma unroll
    for (int ni = 0; ni < 4; ++ni)
#pragma unroll
      for (int kk = 0; kk < 2; ++kk) {
        const int rr = wc * 64 + ni * 16 + fr;
        const int s16 = (kk * 4 + fq) ^ (rr & 7);
        bf[ni][kk] = *(const s16x8*)&LB[rr * 64 + s16 * 8];
      }
#pragma unroll
    for (int kk = 0; kk < 2; ++kk)   // kk outer: dep distance 16
#pragma unroll
      for (int mi = 0; mi < 4; ++mi)
#pragma unroll
        for (int ni = 0; ni < 4; ++ni)
          acc[mi][ni] = MFMA16(af[mi][kk], bf[ni][kk], acc[mi][ni]);
    __syncthreads();                 // reads done before next stage overwrites
  }

  // epilogue: D(i,j): col = lane&15, row = (lane>>4)*4 + reg  [m89-verified]
  if (QKV) {
    u16* Ob = (n0 < 4096) ? O0 : (n0 < 8192 ? O1 : O2);
    const int nc = n0 & 4095;
#pragma unroll
    for (int mi = 0; mi < 4; ++mi)
#pragma unroll
      for (int ni = 0; ni < 4; ++ni) {
        const int col = nc + wc * 64 + ni * 16 + fr;
#pragma unroll
        for (int r = 0; r < 4; ++r) {
          const int row = m0 + wr * 64 + mi * 16 + fq * 4 + r;
          Ob[(size_t)row * 4096 + col] = f2bf(acc[mi][ni][r]);
        }
      }
  } else {
    const int Nn = NB * 128;
#pragma unroll
    for (int mi = 0; mi < 4; ++mi)
#pragma unroll
      for (int ni = 0; ni < 4; ++ni) {
        const int col = n0 + wc * 64 + ni * 16 + fr;
#pragma unroll
        for (int r = 0; r < 4; ++r) {
          const int row = m0 + wr * 64 + mi * 16 + fq * 4 + r;
          Of[(size_t)row * Nn + col] = acc[mi][ni][r];
        }
      }
  }
}

// ---------------- RoPE in-place on bf16 q/k (host-provided cos/sin) --------
__global__ __launch_bounds__(256) void rope_k(u16* __restrict__ q,
                                              u16* __restrict__ k,
                                              const float* __restrict__ cosb,
                                              const float* __restrict__ sinb) {
  u16* t = blockIdx.y ? k : q;
  size_t idx = ((size_t)blockIdx.x * 256 + threadIdx.x) * 8;
  int s  = (int)((idx / D_) % S_);
  int d  = (int)(idx & (HD_ - 1));
  int i0 = d >> 1;
  u16 u[8];
  *(uint4*)u = *(const uint4*)&t[idx];
  float4 c  = *(const float4*)&cosb[s * (HD_ / 2) + i0];
  float4 sn = *(const float4*)&sinb[s * (HD_ / 2) + i0];
  float cs[4] = {c.x, c.y, c.z, c.w}, ss[4] = {sn.x, sn.y, sn.z, sn.w};
#pragma unroll
  for (int p = 0; p < 4; ++p) {
    float t0 = bf2f(u[2 * p]), t1 = bf2f(u[2 * p + 1]);
    u[2 * p]     = f2bf(t0 * cs[p] - t1 * ss[p]);
    u[2 * p + 1] = f2bf(t0 * ss[p] + t1 * cs[p]);
  }
  *(uint4*)&t[idx] = *(uint4*)u;
}

// ---------------- V transpose: (b,s,h,d) -> (b,h,d,s) ----------------------
__global__ __launch_bounds__(256) void transpose_v(const u16* __restrict__ v,
                                                   u16* __restrict__ vt) {
  __shared__ u16 tile[32][33];
  int s0 = blockIdx.x * 32, d0 = blockIdx.y * 32;
  int b = blockIdx.z / H_, h = blockIdx.z % H_;
  int tx = threadIdx.x & 31, ty = threadIdx.x >> 5;
#pragma unroll
  for (int r = 0; r < 32; r += 8)
    tile[ty + r][tx] = v[(size_t)(b * S_ + s0 + ty + r) * D_ + h * HD_ + d0 + tx];
  __syncthreads();
#pragma unroll
  for (int r = 0; r < 32; r += 8)
    vt[(size_t)((b * H_ + h) * HD_ + d0 + ty + r) * S_ + s0 + tx] = tile[tx][ty + r];
}

// ---------------- Flash attention: Q-tile 128, 8 waves x 16 q-rows ---------
__global__ __launch_bounds__(512) void flash_attn(const u16* __restrict__ qb,
                                                  const u16* __restrict__ kb,
                                                  const u16* __restrict__ vtb,
                                                  u16* __restrict__ ab) {
  __shared__ __align__(16) u16 Ks[64][136];
  __shared__ __align__(16) u16 Vs[128][72];
  __shared__ __align__(16) u16 Ps[8][16][72];
  const int qt = blockIdx.x, h = blockIdx.y, b = blockIdx.z;
  const int tid = threadIdx.x, wid = tid >> 6, lane = tid & 63;
  const int fr = lane & 15, fq = lane >> 4;
  const int q0 = qt * 128 + wid * 16;
  s16x8 qf[4];
  {
    size_t base = (size_t)(b * S_ + q0 + fr) * D_ + h * HD_;
#pragma unroll
    for (int kk = 0; kk < 4; ++kk) qf[kk] = *(const s16x8*)&qb[base + kk * 32 + fq * 8];
  }
  f32x4 oacc[8] = {};
  float m_i[4] = {-1e30f, -1e30f, -1e30f, -1e30f};
  float l_i[4] = {0.f, 0.f, 0.f, 0.f};
  const float sc = 0.08838834764831845f;  // 1/sqrt(128)

  for (int k0 = 0; k0 < S_; k0 += 64) {
    __syncthreads();
    for (int c = tid; c < 1024; c += 512) {
      int row = c >> 4, col = (c & 15) * 8;
      *(uint4*)&Ks[row][col] =
          *(const uint4*)&kb[(size_t)(b * S_ + k0 + row) * D_ + h * HD_ + col];
    }
    for (int c = tid; c < 1024; c += 512) {
      int row = c >> 3, col = (c & 7) * 8;
      *(uint4*)&Vs[row][col] =
          *(const uint4*)&vtb[(size_t)((b * H_ + h) * HD_ + row) * S_ + k0 + col];
    }
    __syncthreads();
    f32x4 sacc[4] = {};
#pragma unroll
    for (int kk = 0; kk < 4; ++kk)
#pragma unroll
      for (int nb = 0; nb < 4; ++nb)
        sacc[nb] = MFMA16(qf[kk], *(const s16x8*)&Ks[nb * 16 + fr][kk * 32 + fq * 8],
                          sacc[nb]);
#pragma unroll
    for (int r = 0; r < 4; ++r) {
      float s0 = sacc[0][r] * sc, s1 = sacc[1][r] * sc;
      float s2 = sacc[2][r] * sc, s3 = sacc[3][r] * sc;
      float mx = fmaxf(fmaxf(s0, s1), fmaxf(s2, s3));
#pragma unroll
      for (int o = 1; o < 16; o <<= 1) mx = fmaxf(mx, __shfl_xor(mx, o));
      float newm = fmaxf(m_i[r], mx);
      float fsc = __expf(m_i[r] - newm);
      m_i[r] = newm;
      float p0 = __expf(s0 - newm), p1 = __expf(s1 - newm);
      float p2 = __expf(s2 - newm), p3 = __expf(s3 - newm);
      float sum = p0 + p1 + p2 + p3;
#pragma unroll
      for (int o = 1; o < 16; o <<= 1) sum += __shfl_xor(sum, o);
      l_i[r] = l_i[r] * fsc + sum;
#pragma unroll
      for (int db = 0; db < 8; ++db) oacc[db][r] *= fsc;
      Ps[wid][fq * 4 + r][0 * 16 + fr] = f2bf(p0);
      Ps[wid][fq * 4 + r][1 * 16 + fr] = f2bf(p1);
      Ps[wid][fq * 4 + r][2 * 16 + fr] = f2bf(p2);
      Ps[wid][fq * 4 + r][3 * 16 + fr] = f2bf(p3);
    }
    s16x8 pf0 = *(const s16x8*)&Ps[wid][fr][fq * 8];
    s16x8 pf1 = *(const s16x8*)&Ps[wid][fr][32 + fq * 8];
#pragma unroll
    for (int db = 0; db < 8; ++db)
      oacc[db] = MFMA16(pf0, *(const s16x8*)&Vs[db * 16 + fr][fq * 8], oacc[db]);
#pragma unroll
    for (int db = 0; db < 8; ++db)
      oacc[db] = MFMA16(pf1, *(const s16x8*)&Vs[db * 16 + fr][32 + fq * 8], oacc[db]);
  }
#pragma unroll
  for (int r = 0; r < 4; ++r) {
    float inv = 1.0f / l_i[r];
    size_t rowbase = (size_t)(b * S_ + q0 + fq * 4 + r) * D_ + h * HD_;
#pragma unroll
    for (int db = 0; db < 8; ++db)
      ab[rowbase + db * 16 + fr] = f2bf(oacc[db][r] * inv);
  }
}

// ---------------------------------------------------------------------------
extern "C" void kernel_launch(void* const* d_in, const int* in_sizes, int n_in,
                              void* d_out, int out_size, void* d_ws, size_t ws_size,
                              hipStream_t stream) {
  const float* x    = (const float*)d_in[0];
  const float* wq   = (const float*)d_in[1];
  const float* wk   = (const float*)d_in[2];
  const float* wv   = (const float*)d_in[3];
  const float* wo   = (const float*)d_in[4];
  const float* fcos = (const float*)d_in[7];
  const float* fsin = (const float*)d_in[8];
  float* out = (float*)d_out;

  u16* xb  = (u16*)d_ws;                      // T*D
  u16* wqb = xb + (size_t)T_ * D_;            // D*D each; wq|wk|wv CONTIGUOUS
  u16* wkb = wqb + (size_t)D_ * D_;
  u16* wvb = wkb + (size_t)D_ * D_;
  u16* wob = wvb + (size_t)D_ * D_;
  u16* qb  = wob + (size_t)D_ * D_;           // T*D each
  u16* kb  = qb + (size_t)T_ * D_;
  u16* vb  = kb + (size_t)T_ * D_;
  u16* vtb = vb + (size_t)T_ * D_;
  u16* ab  = vtb + (size_t)T_ * D_;

  cvt_bf16<<<T_ * D_ / 8 / 256, 256, 0, stream>>>(x, xb, T_ * D_ / 8);
  cvt_bf16<<<D_ * D_ / 8 / 256, 256, 0, stream>>>(wq, wqb, D_ * D_ / 8);
  cvt_bf16<<<D_ * D_ / 8 / 256, 256, 0, stream>>>(wk, wkb, D_ * D_ / 8);
  cvt_bf16<<<D_ * D_ / 8 / 256, 256, 0, stream>>>(wv, wvb, D_ * D_ / 8);
  cvt_bf16<<<D_ * D_ / 8 / 256, 256, 0, stream>>>(wo, wob, D_ * D_ / 8);

  // fused QKV: M=2048, N=12288, K=4096 -> 16x96 = 1536 blocks (6/CU)
  gemm_m97<1><<<1536, 256, 0, stream>>>(xb, wqb, qb, kb, vb, nullptr, 16, 96, D_);

  rope_k<<<dim3(T_ * D_ / 8 / 256, 2), 256, 0, stream>>>(qb, kb, fcos, fsin);
  transpose_v<<<dim3(S_ / 32, HD_ / 32, B_ * H_), 256, 0, stream>>>(vb, vtb);
  flash_attn<<<dim3(S_ / 128, H_, B_), 512, 0, stream>>>(qb, kb, vtb, ab);

  // output projection: M=2048, N=4096 -> 16x32 = 512 blocks (2/CU)
  gemm_m97<0><<<512, 256, 0, stream>>>(ab, wob, nullptr, nullptr, nullptr, out, 16, 32, D_);
}

// Round 6
// 506.304 us; speedup vs baseline: 1.1738x; 1.0985x over previous
//
#include <hip/hip_runtime.h>

#define B_  2
#define S_  1024
#define D_  4096
#define H_  32
#define HD_ 128
#define T_  (B_*S_)   // 2048 tokens

typedef short s16x8 __attribute__((ext_vector_type(8)));   // 8 bf16 (4 VGPRs)
typedef float f32x4 __attribute__((ext_vector_type(4)));
typedef unsigned short u16;

__device__ __forceinline__ u16 f2bf(float f) {
  unsigned int u = __float_as_uint(f);
  u += 0x7fffu + ((u >> 16) & 1u);     // round-to-nearest-even
  return (u16)(u >> 16);
}
__device__ __forceinline__ float bf2f(u16 h) {
  return __uint_as_float(((unsigned int)h) << 16);
}
__device__ __forceinline__ void gload_lds16(const void* g, void* l) {
  __builtin_amdgcn_global_load_lds(
      (const __attribute__((address_space(1))) unsigned int*)g,
      (__attribute__((address_space(3))) unsigned int*)l, 16, 0, 0);
}
#define MFMA16(a, b, c) __builtin_amdgcn_mfma_f32_16x16x32_bf16((a), (b), (c), 0, 0, 0)

// ---------------- f32 -> bf16 convert (vectorized, 8 elem/thread) ----------
__global__ __launch_bounds__(256) void cvt_bf16(const float* __restrict__ in,
                                                u16* __restrict__ out, int n8) {
  int i = blockIdx.x * 256 + threadIdx.x;
  if (i >= n8) return;
  const float4* p = (const float4*)in + (size_t)i * 2;
  float4 a = p[0], b = p[1];
  u16 us[8] = {f2bf(a.x), f2bf(a.y), f2bf(a.z), f2bf(a.w),
               f2bf(b.x), f2bf(b.y), f2bf(b.z), f2bf(b.w)};
  *(uint4*)(out + (size_t)i * 8) = *(uint4*)us;
}

// ---- stage one 128x64 bf16 tile with 4 waves (4 chunks of 8 rows each).
// Linear LDS dest (row-major [128][64]), pre-swizzled global source:
// stored 16B-slot s at row r holds logical col16 s^(r&7)  [T2, conflicts=0]
__device__ __forceinline__ void stage_tile4(const u16* __restrict__ g, int ldk,
                                            int row0, int k0, u16* lds,
                                            int wid, int lane) {
  const int rsub = lane >> 3;           // 0..7 row within chunk
  const int c16  = (lane & 7) ^ rsub;   // pre-swizzled source col16
#pragma unroll
  for (int l = 0; l < 4; ++l) {
    const int c = wid * 4 + l;          // chunk 0..15
    gload_lds16(g + (size_t)(row0 + c * 8 + rsub) * ldk + k0 + c16 * 8,
                lds + c * 512);
  }
}

// ---------- m97-style 128x128 GEMM, C = A[M,K] * W[N,K]^T, bf16 ------------
// 4 waves (2x2), 64x64/wave, BK=64, single-buffered LDS, builtin MFMA.
// Register diet: bf[4][2] loaded once (32 regs), af per-mi (8 regs), acc 64.
// __launch_bounds__(256,3): pin 3 waves/SIMD -> 3 blocks/CU co-resident.
// N-fastest XCD chunking: A-panel L2-resident, W streamed once per XCD.
template <int QKV>
__global__ __launch_bounds__(256, 3) void gemm_m97(const u16* __restrict__ A,
                                                   const u16* __restrict__ W,
                                                   u16* __restrict__ O0,
                                                   u16* __restrict__ O1,
                                                   u16* __restrict__ O2,
                                                   float* __restrict__ Of,
                                                   int MB, int NB, int K) {
  __shared__ __align__(16) u16 LA[128 * 64];
  __shared__ __align__(16) u16 LB[128 * 64];
  const int nwg = MB * NB;                        // %8 == 0 for both grids
  const int cpx = nwg >> 3;
  const int bid = blockIdx.x;
  const int swz = (bid & 7) * cpx + (bid >> 3);   // T1: XCD chunking
  const int bm = swz / NB, bn = swz % NB;         // N-fastest: A-panel in L2
  const int m0 = bm * 128, n0 = bn * 128;
  const int tid = threadIdx.x, wid = tid >> 6, lane = tid & 63;
  const int wr = wid >> 1, wc = wid & 1;          // 2x2 waves, 64x64 each
  const int fr = lane & 15, fq = lane >> 4;
  f32x4 acc[4][4] = {};

  for (int k0 = 0; k0 < K; k0 += 64) {
    stage_tile4(A, K, m0, k0, LA, wid, lane);
    stage_tile4(W, K, n0, k0, LB, wid, lane);
    __syncthreads();                 // drains vmcnt: tiles resident
    s16x8 bf[4][2];
#pragma unroll
    for (int ni = 0; ni < 4; ++ni)
#pragma unroll
      for (int kk = 0; kk < 2; ++kk) {
        const int rr = wc * 64 + ni * 16 + fr;
        const int s16 = (kk * 4 + fq) ^ (rr & 7);
        bf[ni][kk] = *(const s16x8*)&LB[rr * 64 + s16 * 8];
      }
#pragma unroll
    for (int mi = 0; mi < 4; ++mi) {  // af transient: 8 regs live at a time
      const int r = wr * 64 + mi * 16 + fr;
      const s16x8 a0 = *(const s16x8*)&LA[r * 64 + ((0 + fq) ^ (r & 7)) * 8];
      const s16x8 a1 = *(const s16x8*)&LA[r * 64 + ((4 + fq) ^ (r & 7)) * 8];
#pragma unroll
      for (int ni = 0; ni < 4; ++ni)  // dep distance 4 within acc[mi][*]
        acc[mi][ni] = MFMA16(a0, bf[ni][0], acc[mi][ni]);
#pragma unroll
      for (int ni = 0; ni < 4; ++ni)
        acc[mi][ni] = MFMA16(a1, bf[ni][1], acc[mi][ni]);
    }
    __syncthreads();                 // reads done before next stage overwrites
  }

  // epilogue: D(i,j): col = lane&15, row = (lane>>4)*4 + reg  [m89-verified]
  if (QKV) {
    u16* Ob = (n0 < 4096) ? O0 : (n0 < 8192 ? O1 : O2);
    const int nc = n0 & 4095;
#pragma unroll
    for (int mi = 0; mi < 4; ++mi)
#pragma unroll
      for (int ni = 0; ni < 4; ++ni) {
        const int col = nc + wc * 64 + ni * 16 + fr;
#pragma unroll
        for (int r = 0; r < 4; ++r) {
          const int row = m0 + wr * 64 + mi * 16 + fq * 4 + r;
          Ob[(size_t)row * 4096 + col] = f2bf(acc[mi][ni][r]);
        }
      }
  } else {
    const int Nn = NB * 128;
#pragma unroll
    for (int mi = 0; mi < 4; ++mi)
#pragma unroll
      for (int ni = 0; ni < 4; ++ni) {
        const int col = n0 + wc * 64 + ni * 16 + fr;
#pragma unroll
        for (int r = 0; r < 4; ++r) {
          const int row = m0 + wr * 64 + mi * 16 + fq * 4 + r;
          Of[(size_t)row * Nn + col] = acc[mi][ni][r];
        }
      }
  }
}

// ---------------- RoPE in-place on bf16 q/k (host-provided cos/sin) --------
__global__ __launch_bounds__(256) void rope_k(u16* __restrict__ q,
                                              u16* __restrict__ k,
                                              const float* __restrict__ cosb,
                                              const float* __restrict__ sinb) {
  u16* t = blockIdx.y ? k : q;
  size_t idx = ((size_t)blockIdx.x * 256 + threadIdx.x) * 8;
  int s  = (int)((idx / D_) % S_);
  int d  = (int)(idx & (HD_ - 1));
  int i0 = d >> 1;
  u16 u[8];
  *(uint4*)u = *(const uint4*)&t[idx];
  float4 c  = *(const float4*)&cosb[s * (HD_ / 2) + i0];
  float4 sn = *(const float4*)&sinb[s * (HD_ / 2) + i0];
  float cs[4] = {c.x, c.y, c.z, c.w}, ss[4] = {sn.x, sn.y, sn.z, sn.w};
#pragma unroll
  for (int p = 0; p < 4; ++p) {
    float t0 = bf2f(u[2 * p]), t1 = bf2f(u[2 * p + 1]);
    u[2 * p]     = f2bf(t0 * cs[p] - t1 * ss[p]);
    u[2 * p + 1] = f2bf(t0 * ss[p] + t1 * cs[p]);
  }
  *(uint4*)&t[idx] = *(uint4*)u;
}

// ---------------- V transpose: (b,s,h,d) -> (b,h,d,s) ----------------------
__global__ __launch_bounds__(256) void transpose_v(const u16* __restrict__ v,
                                                   u16* __restrict__ vt) {
  __shared__ u16 tile[32][33];
  int s0 = blockIdx.x * 32, d0 = blockIdx.y * 32;
  int b = blockIdx.z / H_, h = blockIdx.z % H_;
  int tx = threadIdx.x & 31, ty = threadIdx.x >> 5;
#pragma unroll
  for (int r = 0; r < 32; r += 8)
    tile[ty + r][tx] = v[(size_t)(b * S_ + s0 + ty + r) * D_ + h * HD_ + d0 + tx];
  __syncthreads();
#pragma unroll
  for (int r = 0; r < 32; r += 8)
    vt[(size_t)((b * H_ + h) * HD_ + d0 + ty + r) * S_ + s0 + tx] = tile[tx][ty + r];
}

// ---------------- Flash attention: Q-tile 128, 8 waves x 16 q-rows ---------
__global__ __launch_bounds__(512) void flash_attn(const u16* __restrict__ qb,
                                                  const u16* __restrict__ kb,
                                                  const u16* __restrict__ vtb,
                                                  u16* __restrict__ ab) {
  __shared__ __align__(16) u16 Ks[64][136];
  __shared__ __align__(16) u16 Vs[128][72];
  __shared__ __align__(16) u16 Ps[8][16][72];
  const int qt = blockIdx.x, h = blockIdx.y, b = blockIdx.z;
  const int tid = threadIdx.x, wid = tid >> 6, lane = tid & 63;
  const int fr = lane & 15, fq = lane >> 4;
  const int q0 = qt * 128 + wid * 16;
  s16x8 qf[4];
  {
    size_t base = (size_t)(b * S_ + q0 + fr) * D_ + h * HD_;
#pragma unroll
    for (int kk = 0; kk < 4; ++kk) qf[kk] = *(const s16x8*)&qb[base + kk * 32 + fq * 8];
  }
  f32x4 oacc[8] = {};
  float m_i[4] = {-1e30f, -1e30f, -1e30f, -1e30f};
  float l_i[4] = {0.f, 0.f, 0.f, 0.f};
  const float sc = 0.08838834764831845f;  // 1/sqrt(128)

  for (int k0 = 0; k0 < S_; k0 += 64) {
    __syncthreads();
    for (int c = tid; c < 1024; c += 512) {
      int row = c >> 4, col = (c & 15) * 8;
      *(uint4*)&Ks[row][col] =
          *(const uint4*)&kb[(size_t)(b * S_ + k0 + row) * D_ + h * HD_ + col];
    }
    for (int c = tid; c < 1024; c += 512) {
      int row = c >> 3, col = (c & 7) * 8;
      *(uint4*)&Vs[row][col] =
          *(const uint4*)&vtb[(size_t)((b * H_ + h) * HD_ + row) * S_ + k0 + col];
    }
    __syncthreads();
    f32x4 sacc[4] = {};
#pragma unroll
    for (int kk = 0; kk < 4; ++kk)
#pragma unroll
      for (int nb = 0; nb < 4; ++nb)
        sacc[nb] = MFMA16(qf[kk], *(const s16x8*)&Ks[nb * 16 + fr][kk * 32 + fq * 8],
                          sacc[nb]);
#pragma unroll
    for (int r = 0; r < 4; ++r) {
      float s0 = sacc[0][r] * sc, s1 = sacc[1][r] * sc;
      float s2 = sacc[2][r] * sc, s3 = sacc[3][r] * sc;
      float mx = fmaxf(fmaxf(s0, s1), fmaxf(s2, s3));
#pragma unroll
      for (int o = 1; o < 16; o <<= 1) mx = fmaxf(mx, __shfl_xor(mx, o));
      float newm = fmaxf(m_i[r], mx);
      float fsc = __expf(m_i[r] - newm);
      m_i[r] = newm;
      float p0 = __expf(s0 - newm), p1 = __expf(s1 - newm);
      float p2 = __expf(s2 - newm), p3 = __expf(s3 - newm);
      float sum = p0 + p1 + p2 + p3;
#pragma unroll
      for (int o = 1; o < 16; o <<= 1) sum += __shfl_xor(sum, o);
      l_i[r] = l_i[r] * fsc + sum;
#pragma unroll
      for (int db = 0; db < 8; ++db) oacc[db][r] *= fsc;
      Ps[wid][fq * 4 + r][0 * 16 + fr] = f2bf(p0);
      Ps[wid][fq * 4 + r][1 * 16 + fr] = f2bf(p1);
      Ps[wid][fq * 4 + r][2 * 16 + fr] = f2bf(p2);
      Ps[wid][fq * 4 + r][3 * 16 + fr] = f2bf(p3);
    }
    s16x8 pf0 = *(const s16x8*)&Ps[wid][fr][fq * 8];
    s16x8 pf1 = *(const s16x8*)&Ps[wid][fr][32 + fq * 8];
#pragma unroll
    for (int db = 0; db < 8; ++db)
      oacc[db] = MFMA16(pf0, *(const s16x8*)&Vs[db * 16 + fr][fq * 8], oacc[db]);
#pragma unroll
    for (int db = 0; db < 8; ++db)
      oacc[db] = MFMA16(pf1, *(const s16x8*)&Vs[db * 16 + fr][32 + fq * 8], oacc[db]);
  }
#pragma unroll
  for (int r = 0; r < 4; ++r) {
    float inv = 1.0f / l_i[r];
    size_t rowbase = (size_t)(b * S_ + q0 + fq * 4 + r) * D_ + h * HD_;
#pragma unroll
    for (int db = 0; db < 8; ++db)
      ab[rowbase + db * 16 + fr] = f2bf(oacc[db][r] * inv);
  }
}

// ---------------------------------------------------------------------------
extern "C" void kernel_launch(void* const* d_in, const int* in_sizes, int n_in,
                              void* d_out, int out_size, void* d_ws, size_t ws_size,
                              hipStream_t stream) {
  const float* x    = (const float*)d_in[0];
  const float* wq   = (const float*)d_in[1];
  const float* wk   = (const float*)d_in[2];
  const float* wv   = (const float*)d_in[3];
  const float* wo   = (const float*)d_in[4];
  const float* fcos = (const float*)d_in[7];
  const float* fsin = (const float*)d_in[8];
  float* out = (float*)d_out;

  u16* xb  = (u16*)d_ws;                      // T*D
  u16* wqb = xb + (size_t)T_ * D_;            // D*D each; wq|wk|wv CONTIGUOUS
  u16* wkb = wqb + (size_t)D_ * D_;
  u16* wvb = wkb + (size_t)D_ * D_;
  u16* wob = wvb + (size_t)D_ * D_;
  u16* qb  = wob + (size_t)D_ * D_;           // T*D each
  u16* kb  = qb + (size_t)T_ * D_;
  u16* vb  = kb + (size_t)T_ * D_;
  u16* vtb = vb + (size_t)T_ * D_;
  u16* ab  = vtb + (size_t)T_ * D_;

  cvt_bf16<<<T_ * D_ / 8 / 256, 256, 0, stream>>>(x, xb, T_ * D_ / 8);
  cvt_bf16<<<D_ * D_ / 8 / 256, 256, 0, stream>>>(wq, wqb, D_ * D_ / 8);
  cvt_bf16<<<D_ * D_ / 8 / 256, 256, 0, stream>>>(wk, wkb, D_ * D_ / 8);
  cvt_bf16<<<D_ * D_ / 8 / 256, 256, 0, stream>>>(wv, wvb, D_ * D_ / 8);
  cvt_bf16<<<D_ * D_ / 8 / 256, 256, 0, stream>>>(wo, wob, D_ * D_ / 8);

  // fused QKV: M=2048, N=12288, K=4096 -> 16x96 = 1536 blocks (6/CU)
  gemm_m97<1><<<1536, 256, 0, stream>>>(xb, wqb, qb, kb, vb, nullptr, 16, 96, D_);

  rope_k<<<dim3(T_ * D_ / 8 / 256, 2), 256, 0, stream>>>(qb, kb, fcos, fsin);
  transpose_v<<<dim3(S_ / 32, HD_ / 32, B_ * H_), 256, 0, stream>>>(vb, vtb);
  flash_attn<<<dim3(S_ / 128, H_, B_), 512, 0, stream>>>(qb, kb, vtb, ab);

  // output projection: M=2048, N=4096 -> 16x32 = 512 blocks (2/CU)
  gemm_m97<0><<<512, 256, 0, stream>>>(ab, wob, nullptr, nullptr, nullptr, out, 16, 32, D_);
}

// Round 7
// 484.947 us; speedup vs baseline: 1.2255x; 1.0440x over previous
//
#include <hip/hip_runtime.h>

#define B_  2
#define S_  1024
#define D_  4096
#define H_  32
#define HD_ 128
#define T_  (B_*S_)   // 2048 tokens

typedef short s16x8 __attribute__((ext_vector_type(8)));   // 8 bf16 (4 VGPRs)
typedef float f32x4 __attribute__((ext_vector_type(4)));
typedef unsigned short u16;

__device__ __forceinline__ u16 f2bf(float f) {
  unsigned int u = __float_as_uint(f);
  u += 0x7fffu + ((u >> 16) & 1u);     // round-to-nearest-even
  return (u16)(u >> 16);
}
__device__ __forceinline__ float bf2f(u16 h) {
  return __uint_as_float(((unsigned int)h) << 16);
}
__device__ __forceinline__ void gload_lds16(const void* g, void* l) {
  __builtin_amdgcn_global_load_lds(
      (const __attribute__((address_space(1))) unsigned int*)g,
      (__attribute__((address_space(3))) unsigned int*)l, 16, 0, 0);
}
#define MFMA16(a, b, c) __builtin_amdgcn_mfma_f32_16x16x32_bf16((a), (b), (c), 0, 0, 0)

// ---------------- f32 -> bf16 convert (vectorized, 8 elem/thread) ----------
__global__ __launch_bounds__(256) void cvt_bf16(const float* __restrict__ in,
                                                u16* __restrict__ out, int n8) {
  int i = blockIdx.x * 256 + threadIdx.x;
  if (i >= n8) return;
  const float4* p = (const float4*)in + (size_t)i * 2;
  float4 a = p[0], b = p[1];
  u16 us[8] = {f2bf(a.x), f2bf(a.y), f2bf(a.z), f2bf(a.w),
               f2bf(b.x), f2bf(b.y), f2bf(b.z), f2bf(b.w)};
  *(uint4*)(out + (size_t)i * 8) = *(uint4*)us;
}

// ---- stage one 128x64 bf16 tile, NW waves. Linear LDS dest [128][64],
// pre-swizzled source: stored 16B-slot s at row r holds logical col16 s^(r&7)
template <int NW>
__device__ __forceinline__ void stage_tile(const u16* __restrict__ g, int ldk,
                                           int row0, int k0, u16* lds,
                                           int wid, int lane) {
  const int rsub = lane >> 3;           // 0..7 row within chunk
  const int c16  = (lane & 7) ^ rsub;   // pre-swizzled source col16
#pragma unroll
  for (int l = 0; l < 16 / NW; ++l) {
    const int c = wid * (16 / NW) + l;  // chunk 0..15 (8 rows each)
    gload_lds16(g + (size_t)(row0 + c * 8 + rsub) * ldk + k0 + c16 * 8,
                lds + c * 512);
  }
}

// ========== QKV GEMM: m97 structure (R6-proven, 877 TF) + fused epilogue ====
// C = A[M,K] * W[N,K]^T. Epilogue: Q/K cols get RoPE (pairs = adjacent lanes,
// one shfl_xor); V cols written directly transposed to (b,h,d,s).
__global__ __launch_bounds__(256, 3) void gemm_qkv(const u16* __restrict__ A,
                                                   const u16* __restrict__ W,
                                                   u16* __restrict__ Oq,
                                                   u16* __restrict__ Ok,
                                                   u16* __restrict__ Ovt,
                                                   const float* __restrict__ cosb,
                                                   const float* __restrict__ sinb,
                                                   int MB, int NB, int K) {
  __shared__ __align__(16) u16 LA[128 * 64];
  __shared__ __align__(16) u16 LB[128 * 64];
  const int nwg = MB * NB;                        // %8 == 0
  const int cpx = nwg >> 3;
  const int bid = blockIdx.x;
  const int swz = (bid & 7) * cpx + (bid >> 3);   // T1: XCD chunking
  const int bm = swz / NB, bn = swz % NB;         // N-fastest (R6-proven)
  const int m0 = bm * 128, n0 = bn * 128;
  const int tid = threadIdx.x, wid = tid >> 6, lane = tid & 63;
  const int wr = wid >> 1, wc = wid & 1;          // 2x2 waves, 64x64 each
  const int fr = lane & 15, fq = lane >> 4;
  f32x4 acc[4][4] = {};

  for (int k0 = 0; k0 < K; k0 += 64) {
    stage_tile<4>(A, K, m0, k0, LA, wid, lane);
    stage_tile<4>(W, K, n0, k0, LB, wid, lane);
    __syncthreads();
    s16x8 bf[4][2];
#pragma unroll
    for (int ni = 0; ni < 4; ++ni)
#pragma unroll
      for (int kk = 0; kk < 2; ++kk) {
        const int rr = wc * 64 + ni * 16 + fr;
        const int s16 = (kk * 4 + fq) ^ (rr & 7);
        bf[ni][kk] = *(const s16x8*)&LB[rr * 64 + s16 * 8];
      }
#pragma unroll
    for (int mi = 0; mi < 4; ++mi) {
      const int r = wr * 64 + mi * 16 + fr;
      const s16x8 a0 = *(const s16x8*)&LA[r * 64 + ((0 + fq) ^ (r & 7)) * 8];
      const s16x8 a1 = *(const s16x8*)&LA[r * 64 + ((4 + fq) ^ (r & 7)) * 8];
#pragma unroll
      for (int ni = 0; ni < 4; ++ni)
        acc[mi][ni] = MFMA16(a0, bf[ni][0], acc[mi][ni]);
#pragma unroll
      for (int ni = 0; ni < 4; ++ni)
        acc[mi][ni] = MFMA16(a1, bf[ni][1], acc[mi][ni]);
    }
    __syncthreads();
  }

  // epilogue: D(i,j): col = lane&15, row = (lane>>4)*4 + reg
  if (n0 < 8192) {                       // ---- Q or K: fused RoPE ----
    u16* Ob = (n0 < 4096) ? Oq : Ok;
    const int nc = n0 & 4095;
    const float sgn = (fr & 1) ? 1.f : -1.f;   // even lane: t0*c - t1*s
#pragma unroll
    for (int mi = 0; mi < 4; ++mi)
#pragma unroll
      for (int ni = 0; ni < 4; ++ni) {
        const int col = nc + wc * 64 + ni * 16 + fr;
        const int i0 = (col & (HD_ - 1)) >> 1;
#pragma unroll
        for (int r = 0; r < 4; ++r) {
          const int row = m0 + wr * 64 + mi * 16 + fq * 4 + r;
          const int s = row & (S_ - 1);
          const float v  = acc[mi][ni][r];
          const float vo = __shfl_xor(v, 1);
          const float c  = cosb[s * (HD_ / 2) + i0];
          const float sn = sinb[s * (HD_ / 2) + i0];
          Ob[(size_t)row * 4096 + col] = f2bf(v * c + sgn * vo * sn);
        }
      }
  } else {                               // ---- V: write transposed (b,h,d,s)
    const int nc = n0 - 8192;
#pragma unroll
    for (int mi = 0; mi < 4; ++mi)
#pragma unroll
      for (int ni = 0; ni < 4; ++ni) {
        const int col = nc + wc * 64 + ni * 16 + fr;
        const int h = col >> 7, d = col & (HD_ - 1);
        const int row0 = m0 + wr * 64 + mi * 16 + fq * 4;
        const int bb = row0 >> 10, s0 = row0 & (S_ - 1);
        ushort4 w;
        w.x = f2bf(acc[mi][ni][0]); w.y = f2bf(acc[mi][ni][1]);
        w.z = f2bf(acc[mi][ni][2]); w.w = f2bf(acc[mi][ni][3]);
        *(ushort4*)&Ovt[((size_t)(bb * H_ + h) * HD_ + d) * S_ + s0] = w;
      }
  }
}

// ========== out-proj: 128x256 2-phase counted-vmcnt GEMM, BUILTIN MFMA =====
// A/B experiment: R4 schedule (T1+T2+T3+T4+T5) with builtin MFMA instead of
// inline-asm, no manual lgkmcnt/sched_barrier (compiler tracks ds_reads).
// Parts per K-tile: {B0, B1, A}. 8 waves (2x4), 64x64/wave, f32 out.
__global__ __launch_bounds__(512, 2) void gemm2p_out(const u16* __restrict__ A,
                                                     const u16* __restrict__ W,
                                                     float* __restrict__ Of,
                                                     int MB, int NB, int K) {
  __shared__ __align__(16) u16 LA[2][128 * 64];     // 32KB
  __shared__ __align__(16) u16 LB[2][2][128 * 64];  // 64KB
  const int nwg = MB * NB;
  const int cpx = nwg >> 3;
  const int bid = blockIdx.x;
  const int swz = (bid & 7) * cpx + (bid >> 3);
  const int bm = swz / NB, bn = swz % NB;           // N-fastest
  const int m0 = bm * 128, n0 = bn * 256;
  const int tid = threadIdx.x, wid = tid >> 6, lane = tid & 63;
  const int wr = wid >> 2, wc = wid & 3;            // 2x4 wave grid
  const int fr = lane & 15, fq = lane >> 4;
  const int nkt = K >> 6;
  f32x4 acc[4][4] = {};

  auto STAGE = [&](int gidx) {   // gidx = tile*3 + part, parts {B0,B1,A}
    if (gidx >= 3 * nkt) return;
    const int t = gidx / 3, part = gidx - 3 * t, slot = t & 1, k0 = t * 64;
    if (part < 2)
      stage_tile<8>(W, K, n0 + part * 128, k0, &LB[slot][part][0], wid, lane);
    else
      stage_tile<8>(A, K, m0, k0, &LA[slot][0], wid, lane);
  };

  for (int g = 0; g < 5; ++g) STAGE(g);           // t0 full + t1 {B0,B1}
  asm volatile("s_waitcnt vmcnt(4)" ::: "memory");  // t0 landed
  __builtin_amdgcn_s_barrier();

  for (int t = 0; t < nkt; ++t) {
    const int slot = t & 1;
    s16x8 af[2][2], bfr[4][2];
    // -------- phase 0: mi {0,1}; read all B frags (live both phases)
#pragma unroll
    for (int i = 0; i < 2; ++i)
#pragma unroll
      for (int kk = 0; kk < 2; ++kk) {
        const int r = wr * 64 + i * 16 + fr;
        const int s16 = (kk * 4 + fq) ^ (r & 7);
        af[i][kk] = *(const s16x8*)&LA[slot][r * 64 + s16 * 8];
      }
#pragma unroll
    for (int ni = 0; ni < 4; ++ni)
#pragma unroll
      for (int kk = 0; kk < 2; ++kk) {
        const int rr = (wc & 1) * 64 + ni * 16 + fr;
        const int s16 = (kk * 4 + fq) ^ (rr & 7);
        bfr[ni][kk] = *(const s16x8*)&LB[slot][wc >> 1][rr * 64 + s16 * 8];
      }
    STAGE(3 * t + 5);                    // t+1: A (other slot, WAR-safe)
    __builtin_amdgcn_s_barrier();
    __builtin_amdgcn_s_setprio(1);
#pragma unroll
    for (int kk = 0; kk < 2; ++kk)       // kk outer: dep distance 8
#pragma unroll
      for (int i = 0; i < 2; ++i)
#pragma unroll
        for (int ni = 0; ni < 4; ++ni)
          acc[i][ni] = MFMA16(af[i][kk], bfr[ni][kk], acc[i][ni]);
    __builtin_amdgcn_s_setprio(0);
    __builtin_amdgcn_s_barrier();
    // -------- phase 1: mi {2,3}
#pragma unroll
    for (int i = 0; i < 2; ++i)
#pragma unroll
      for (int kk = 0; kk < 2; ++kk) {
        const int r = wr * 64 + (2 + i) * 16 + fr;
        const int s16 = (kk * 4 + fq) ^ (r & 7);
        af[i][kk] = *(const s16x8*)&LA[slot][r * 64 + s16 * 8];
      }
    STAGE(3 * t + 6);                    // t+2: B0 (post-ph0-barrier WAR-safe)
    STAGE(3 * t + 7);                    // t+2: B1
    if (t < nkt - 2) asm volatile("s_waitcnt vmcnt(4)" ::: "memory"); // t+1 landed
    else             asm volatile("s_waitcnt vmcnt(0)" ::: "memory");
    __builtin_amdgcn_s_barrier();
    __builtin_amdgcn_s_setprio(1);
#pragma unroll
    for (int kk = 0; kk < 2; ++kk)
#pragma unroll
      for (int i = 0; i < 2; ++i)
#pragma unroll
        for (int ni = 0; ni < 4; ++ni)
          acc[2 + i][ni] = MFMA16(af[i][kk], bfr[ni][kk], acc[2 + i][ni]);
    __builtin_amdgcn_s_setprio(0);
    __builtin_amdgcn_s_barrier();
  }

  const int Nn = NB * 256;
#pragma unroll
  for (int mi = 0; mi < 4; ++mi)
#pragma unroll
    for (int ni = 0; ni < 4; ++ni) {
      const int col = n0 + wc * 64 + ni * 16 + fr;
#pragma unroll
      for (int r = 0; r < 4; ++r) {
        const int row = m0 + wr * 64 + mi * 16 + fq * 4 + r;
        Of[(size_t)row * Nn + col] = acc[mi][ni][r];
      }
    }
}

// ---------------- Flash attention: Q-tile 128, 8 waves x 16 q-rows ---------
__global__ __launch_bounds__(512) void flash_attn(const u16* __restrict__ qb,
                                                  const u16* __restrict__ kb,
                                                  const u16* __restrict__ vtb,
                                                  u16* __restrict__ ab) {
  __shared__ __align__(16) u16 Ks[64][136];
  __shared__ __align__(16) u16 Vs[128][72];
  __shared__ __align__(16) u16 Ps[8][16][72];
  const int qt = blockIdx.x, h = blockIdx.y, b = blockIdx.z;
  const int tid = threadIdx.x, wid = tid >> 6, lane = tid & 63;
  const int fr = lane & 15, fq = lane >> 4;
  const int q0 = qt * 128 + wid * 16;
  s16x8 qf[4];
  {
    size_t base = (size_t)(b * S_ + q0 + fr) * D_ + h * HD_;
#pragma unroll
    for (int kk = 0; kk < 4; ++kk) qf[kk] = *(const s16x8*)&qb[base + kk * 32 + fq * 8];
  }
  f32x4 oacc[8] = {};
  float m_i[4] = {-1e30f, -1e30f, -1e30f, -1e30f};
  float l_i[4] = {0.f, 0.f, 0.f, 0.f};
  const float sc = 0.08838834764831845f;  // 1/sqrt(128)

  for (int k0 = 0; k0 < S_; k0 += 64) {
    __syncthreads();
    for (int c = tid; c < 1024; c += 512) {
      int row = c >> 4, col = (c & 15) * 8;
      *(uint4*)&Ks[row][col] =
          *(const uint4*)&kb[(size_t)(b * S_ + k0 + row) * D_ + h * HD_ + col];
    }
    for (int c = tid; c < 1024; c += 512) {
      int row = c >> 3, col = (c & 7) * 8;
      *(uint4*)&Vs[row][col] =
          *(const uint4*)&vtb[(size_t)((b * H_ + h) * HD_ + row) * S_ + k0 + col];
    }
    __syncthreads();
    f32x4 sacc[4] = {};
    __builtin_amdgcn_s_setprio(1);
#pragma unroll
    for (int kk = 0; kk < 4; ++kk)
#pragma unroll
      for (int nb = 0; nb < 4; ++nb)
        sacc[nb] = MFMA16(qf[kk], *(const s16x8*)&Ks[nb * 16 + fr][kk * 32 + fq * 8],
                          sacc[nb]);
    __builtin_amdgcn_s_setprio(0);
#pragma unroll
    for (int r = 0; r < 4; ++r) {
      float s0 = sacc[0][r] * sc, s1 = sacc[1][r] * sc;
      float s2 = sacc[2][r] * sc, s3 = sacc[3][r] * sc;
      float mx = fmaxf(fmaxf(s0, s1), fmaxf(s2, s3));
#pragma unroll
      for (int o = 1; o < 16; o <<= 1) mx = fmaxf(mx, __shfl_xor(mx, o));
      float newm = fmaxf(m_i[r], mx);
      float fsc = __expf(m_i[r] - newm);
      m_i[r] = newm;
      float p0 = __expf(s0 - newm), p1 = __expf(s1 - newm);
      float p2 = __expf(s2 - newm), p3 = __expf(s3 - newm);
      float sum = p0 + p1 + p2 + p3;
#pragma unroll
      for (int o = 1; o < 16; o <<= 1) sum += __shfl_xor(sum, o);
      l_i[r] = l_i[r] * fsc + sum;
#pragma unroll
      for (int db = 0; db < 8; ++db) oacc[db][r] *= fsc;
      Ps[wid][fq * 4 + r][0 * 16 + fr] = f2bf(p0);
      Ps[wid][fq * 4 + r][1 * 16 + fr] = f2bf(p1);
      Ps[wid][fq * 4 + r][2 * 16 + fr] = f2bf(p2);
      Ps[wid][fq * 4 + r][3 * 16 + fr] = f2bf(p3);
    }
    s16x8 pf0 = *(const s16x8*)&Ps[wid][fr][fq * 8];
    s16x8 pf1 = *(const s16x8*)&Ps[wid][fr][32 + fq * 8];
    __builtin_amdgcn_s_setprio(1);
#pragma unroll
    for (int db = 0; db < 8; ++db)
      oacc[db] = MFMA16(pf0, *(const s16x8*)&Vs[db * 16 + fr][fq * 8], oacc[db]);
#pragma unroll
    for (int db = 0; db < 8; ++db)
      oacc[db] = MFMA16(pf1, *(const s16x8*)&Vs[db * 16 + fr][32 + fq * 8], oacc[db]);
    __builtin_amdgcn_s_setprio(0);
  }
#pragma unroll
  for (int r = 0; r < 4; ++r) {
    float inv = 1.0f / l_i[r];
    size_t rowbase = (size_t)(b * S_ + q0 + fq * 4 + r) * D_ + h * HD_;
#pragma unroll
    for (int db = 0; db < 8; ++db)
      ab[rowbase + db * 16 + fr] = f2bf(oacc[db][r] * inv);
  }
}

// ---------------------------------------------------------------------------
extern "C" void kernel_launch(void* const* d_in, const int* in_sizes, int n_in,
                              void* d_out, int out_size, void* d_ws, size_t ws_size,
                              hipStream_t stream) {
  const float* x    = (const float*)d_in[0];
  const float* wq   = (const float*)d_in[1];
  const float* wk   = (const float*)d_in[2];
  const float* wv   = (const float*)d_in[3];
  const float* wo   = (const float*)d_in[4];
  const float* fcos = (const float*)d_in[7];
  const float* fsin = (const float*)d_in[8];
  float* out = (float*)d_out;

  u16* xb  = (u16*)d_ws;                      // T*D
  u16* wqb = xb + (size_t)T_ * D_;            // D*D each; wq|wk|wv CONTIGUOUS
  u16* wkb = wqb + (size_t)D_ * D_;
  u16* wvb = wkb + (size_t)D_ * D_;
  u16* wob = wvb + (size_t)D_ * D_;
  u16* qb  = wob + (size_t)D_ * D_;           // T*D each
  u16* kb  = qb + (size_t)T_ * D_;
  u16* vb  = kb + (size_t)T_ * D_;            // unused (V written transposed)
  u16* vtb = vb + (size_t)T_ * D_;
  u16* ab  = vtb + (size_t)T_ * D_;

  cvt_bf16<<<T_ * D_ / 8 / 256, 256, 0, stream>>>(x, xb, T_ * D_ / 8);
  cvt_bf16<<<D_ * D_ / 8 / 256, 256, 0, stream>>>(wq, wqb, D_ * D_ / 8);
  cvt_bf16<<<D_ * D_ / 8 / 256, 256, 0, stream>>>(wk, wkb, D_ * D_ / 8);
  cvt_bf16<<<D_ * D_ / 8 / 256, 256, 0, stream>>>(wv, wvb, D_ * D_ / 8);
  cvt_bf16<<<D_ * D_ / 8 / 256, 256, 0, stream>>>(wo, wob, D_ * D_ / 8);

  // fused QKV + RoPE + V-transpose: M=2048, N=12288 -> 1536 blocks (6/CU)
  gemm_qkv<<<1536, 256, 0, stream>>>(xb, wqb, qb, kb, vtb, fcos, fsin, 16, 96, D_);

  flash_attn<<<dim3(S_ / 128, H_, B_), 512, 0, stream>>>(qb, kb, vtb, ab);

  // output projection: 2-phase builtin experiment, 16x16 = 256 blocks (1/CU)
  gemm2p_out<<<256, 512, 0, stream>>>(ab, wob, out, 16, 16, D_);
}